// Round 5
// baseline (400.667 us; speedup 1.0000x reference)
//
#include <hip/hip_runtime.h>
#include <stdint.h>

typedef int v4i __attribute__((ext_vector_type(4)));

// Problem constants
constexpr int C     = 256;           // channels (in == out)
constexpr int H     = 28, W = 28;
constexpr int HW    = H * W;         // 784
constexpr int NB    = 64;            // batch
constexpr int GP    = NB * HW;       // 50176 flattened pixels
constexpr int CNT   = GP;            // per-channel reduction count
constexpr int TOTAL = NB * C * HW;   // 12,845,056
constexpr int MT    = 64;            // pixels per block (M-tile)
constexpr int NBLK  = GP / MT;       // 784 pixel-chunks, exact
constexpr int LROWS = 128;           // staged pixel rows: gp0-32 .. gp0+95

// ---------------------------------------------------------------------------
// Pre-pass (1 dispatch): weight packs for both convs in MFMA fragment order
// + activation i8 pack (plane-major) + stats zeroing.
// Frag order for mfma_i32_16x16x64_i8 (same mapping for A and B operands):
// lane l holds co = (group*16 + l&15), k = (l>>4)*16 + e. Stored
// lane-contiguous: wbf[((tp*4+kb)*16+g)*64+l]. +1 -> 0x01, -1 -> 0xFF.
// ---------------------------------------------------------------------------
__global__ void pack_all_kernel(const float* __restrict__ pw1, const float* __restrict__ pw2,
                                const float* __restrict__ x,
                                v4i* __restrict__ wbf1, v4i* __restrict__ wbf2,
                                v4i* __restrict__ xb, double* __restrict__ stats) {
    const int t = threadIdx.x;
    const int bid = blockIdx.x;
    if (bid < 288) {                       // 288*256 = 73728 = 2 * 36864
        const int gid = bid * 256 + t;
        const bool second = (gid >= 36864);
        const float* w = second ? pw2 : pw1;
        v4i* dst       = second ? wbf2 : wbf1;
        const int idx = second ? gid - 36864 : gid;   // ((tp*4+kb)*16+g)*64+l
        const int l  = idx & 63;
        const int g  = (idx >> 6) & 15;
        const int kb = (idx >> 10) & 3;
        const int tp = idx >> 12;          // 0..8
        const int co  = g * 16 + (l & 15);
        const int ci0 = kb * 64 + (l >> 4) * 16;
        int b0 = 0, b1 = 0, b2 = 0, b3 = 0;
#pragma unroll
        for (int e = 0; e < 16; ++e) {
            float v = w[((size_t)co * C + ci0 + e) * 9 + tp];
            int b = (v < 0.f) ? 0xFF : 0x01;
            int sh = (e & 3) * 8;
            if (e < 4) b0 |= b << sh; else if (e < 8) b1 |= b << sh;
            else if (e < 12) b2 |= b << sh; else b3 |= b << sh;
        }
        v4i o; o.x = b0; o.y = b1; o.z = b2; o.w = b3;
        dst[idx] = o;
    } else {
        const int gp = (bid - 288) * 256 + t;   // 196 blocks -> 50176 exact
        if (gp < 1024) stats[gp] = 0.0;         // zero sum1/sumsq1/sum2/sumsq2
        const int n = gp / HW, p = gp % HW;
        const float* base = x + (size_t)n * C * HW + p;
#pragma unroll
        for (int ch = 0; ch < 16; ++ch) {
            int b0 = 0, b1 = 0, b2 = 0, b3 = 0;
#pragma unroll
            for (int e = 0; e < 16; ++e) {
                float v = base[(size_t)(ch * 16 + e) * HW];
                int b = (v < 0.f) ? 0xFF : 0x01;
                int sh = (e & 3) * 8;
                if (e < 4) b0 |= b << sh; else if (e < 8) b1 |= b << sh;
                else if (e < 12) b2 |= b << sh; else b3 |= b << sh;
            }
            v4i o; o.x = b0; o.y = b1; o.z = b2; o.w = b3;
            xb[(size_t)ch * GP + gp] = o;
        }
    }
}

// ---------------------------------------------------------------------------
// Fused finalize (redundant per block) + BN + binarize -> i8 plane-major.
// ---------------------------------------------------------------------------
__global__ void bn_signpack_kernel(const short* __restrict__ y,
                                   const double* __restrict__ sum,
                                   const double* __restrict__ sumsq,
                                   const float* __restrict__ gamma,
                                   const float* __restrict__ beta,
                                   v4i* __restrict__ xb) {
    __shared__ float s_scale[C], s_shift[C];
    const int t = threadIdx.x;
    {
        double mean = sum[t] / (double)CNT;
        double var  = sumsq[t] / (double)CNT - mean * mean;
        double inv  = 1.0 / sqrt(var + 1e-5);
        s_scale[t] = (float)inv * gamma[t];
        s_shift[t] = beta[t] - (float)(mean * inv) * gamma[t];
    }
    __syncthreads();
    const int gp = blockIdx.x * 256 + t;    // grid exact: 196 blocks
    const int n = gp / HW, p = gp % HW;
    const short* base = y + (size_t)n * C * HW + p;
#pragma unroll
    for (int ch = 0; ch < 16; ++ch) {
        int b0 = 0, b1 = 0, b2 = 0, b3 = 0;
#pragma unroll
        for (int e = 0; e < 16; ++e) {
            int c = ch * 16 + e;
            float z = (float)base[(size_t)c * HW] * s_scale[c] + s_shift[c];
            int b = (z < 0.f) ? 0xFF : 0x01;
            int sh = (e & 3) * 8;
            if (e < 4) b0 |= b << sh; else if (e < 8) b1 |= b << sh;
            else if (e < 12) b2 |= b << sh; else b3 |= b << sh;
        }
        v4i o; o.x = b0; o.y = b1; o.z = b2; o.w = b3;
        xb[(size_t)ch * GP + gp] = o;
    }
}

// ---------------------------------------------------------------------------
// R10: implicit-GEMM i8 MFMA, N-split + operand swap.
// R9 post-mortem: MfmaUtil 12.6%, Occupancy 17.5% — grid 784 = 3.06 blk/CU,
// ~1.4 waves/SIMD resident; waits not coverable. WRITE 55 MB vs 25.7 ideal
// (lane=channel scatter stores).
// Fix 1: N-split 2 — block = 64px x 128co, grid (784,2) = 1568 blocks.
// Fix 2: operand swap — mfma(W, X): A/B frags have identical lane mapping,
// so data layouts unchanged; D becomes col=pixel(l&15), row=channel
// (lhi*4+reg) -> stores are 16-lane contiguous-pixel runs (32B i16 / 64B
// f32); conv2 residual loads full lines. Stats via 16-lane shuffle trees.
// ---------------------------------------------------------------------------

#define ACC_DECL v4i c00={0,0,0,0},c01={0,0,0,0}, \
                     c10={0,0,0,0},c11={0,0,0,0}, \
                     c20={0,0,0,0},c21={0,0,0,0}, \
                     c30={0,0,0,0},c31={0,0,0,0};

#define MFMA(a,b,c) c = __builtin_amdgcn_mfma_i32_16x16x64_i8(a, b, c, 0, 0, 0);

// load 2 W-frags (one kb, this wave's 2 co-groups)
#define B_LOADQ(P, idx) { const v4i* bp = wbf + (idx); P##0 = bp[0]; P##1 = bp[64]; }

// read 4 X-frags (one kb: pt=0..3); R* = row*16 (or zero-row 2048), S* = swizzle
#define A_READQ(P, cb) { \
    P##0 = xl[R0 + ((cb) ^ S0)]; P##1 = xl[R1 + ((cb) ^ S1)]; \
    P##2 = xl[R2 + ((cb) ^ S2)]; P##3 = xl[R3 + ((cb) ^ S3)]; }

// 8 MFMAs: c{pt}{cf} = W{cf} * X{pt}
#define MFMA_Q(X, Wf) \
    MFMA(Wf##0, X##0, c00) MFMA(Wf##0, X##1, c10) MFMA(Wf##0, X##2, c20) MFMA(Wf##0, X##3, c30) \
    MFMA(Wf##1, X##0, c01) MFMA(Wf##1, X##1, c11) MFMA(Wf##1, X##2, c21) MFMA(Wf##1, X##3, c31)

// per-tap X addressing (rows*16 with zero-row select + swizzle)
#define TAPVARS(TPX, RD0,RD1,RD2,RD3, SD0,SD1,SD2,SD3) { \
    const int dr = (TPX)/3 - 1, dc = (TPX)%3 - 1; \
    const int lrb = 32 + llo + dr * W + dc; \
    const int sm = lrb & 15; \
    const bool m0 = ((unsigned)(cm0+dc) < 28u) && ((unsigned)(rm0+dr) < 28u); \
    const bool m1 = ((unsigned)(cm1+dc) < 28u) && ((unsigned)(rm1+dr) < 28u); \
    const bool m2 = ((unsigned)(cm2+dc) < 28u) && ((unsigned)(rm2+dr) < 28u); \
    const bool m3 = ((unsigned)(cm3+dc) < 28u) && ((unsigned)(rm3+dr) < 28u); \
    RD0 = m0 ? lrb*16        : 2048; SD0 = m0 ? sm : 0; \
    RD1 = m1 ? lrb*16 + 256  : 2048; SD1 = m1 ? sm : 0; \
    RD2 = m2 ? lrb*16 + 512  : 2048; SD2 = m2 ? sm : 0; \
    RD3 = m3 ? lrb*16 + 768  : 2048; SD3 = m3 ? sm : 0; }

// epilogue: element j of frag (pt,cf): pixel = gp(pt)+llo, chan = base+lhi*4+j
#define EPIS(pt,cf,F,j) { \
    float yv = (float)(c##pt##cf.F); \
    const size_t idx2 = nb##pt + (size_t)(cobase + (cf)*16 + lhi*4 + (j)) * HW; \
    if constexpr (HAS_RES) { yv += residual[idx2]; } \
    yout[idx2] = (OUT_T)yv; \
    s##cf##j += yv; q##cf##j += yv * yv; }
#define EPIP(pt) EPIS(pt,0,x,0) EPIS(pt,0,y,1) EPIS(pt,0,z,2) EPIS(pt,0,w,3) \
                 EPIS(pt,1,x,0) EPIS(pt,1,y,1) EPIS(pt,1,z,2) EPIS(pt,1,w,3)

// reduce across the 16 pixel-lanes (llo) of each lhi group, then atomic
#define REDC(cf,j) { float s1 = s##cf##j, s2 = q##cf##j; \
    s1 += __shfl_down(s1, 8); s1 += __shfl_down(s1, 4); \
    s1 += __shfl_down(s1, 2); s1 += __shfl_down(s1, 1); \
    s2 += __shfl_down(s2, 8); s2 += __shfl_down(s2, 4); \
    s2 += __shfl_down(s2, 2); s2 += __shfl_down(s2, 1); \
    if (llo == 0) { const int co = cobase + (cf)*16 + lhi*4 + (j); \
        atomicAdd(&sum[co], (double)s1); atomicAdd(&sumsq[co], (double)s2); } }

template<bool HAS_RES, typename OUT_T>
__launch_bounds__(256, 4)
__global__ void bconv_mfma(const v4i* __restrict__ xb,
                           const v4i* __restrict__ wbf,
                           const float* __restrict__ residual,
                           OUT_T* __restrict__ yout,
                           double* __restrict__ sum, double* __restrict__ sumsq) {
    __shared__ v4i xl[LROWS * 16 + 16];     // 128 data rows + 1 zero row (33 KB)
    const int t   = threadIdx.x;
    const int gp0 = blockIdx.x * MT;
    const int nh  = blockIdx.y;             // co half: 0 -> 0..127, 1 -> 128..255

    // stage 128 pixel-rows x 16 chunks, coalesced reads, swizzled LDS writes
#pragma unroll
    for (int pass = 0; pass < 8; ++pass) {
        const int i = pass * 256 + t;
        const int c = i >> 7;               // plane 0..15
        const int r = i & 127;              // local row
        int gsrc = min(max(gp0 - 32 + r, 0), GP - 1);
        xl[r * 16 + (c ^ (r & 15))] = xb[(size_t)c * GP + gsrc];
    }
    if (t < 16) { v4i z = {0,0,0,0}; xl[LROWS * 16 + t] = z; }   // zero row
    __syncthreads();

    const int l = t & 63, wn = t >> 6;
    const int llo = l & 15, lhi = l >> 4;

    // per-pixel-tile coords (pixel of X-frag = llo)
    const int gx0 = gp0 + llo, gx1 = gx0 + 16, gx2 = gx0 + 32, gx3 = gx0 + 48;
    const int pm0 = gx0 % HW, pm1 = gx1 % HW, pm2 = gx2 % HW, pm3 = gx3 % HW;
    const int rm0 = pm0 / W, rm1 = pm1 / W, rm2 = pm2 / W, rm3 = pm3 / W;
    const int cm0 = pm0 % W, cm1 = pm1 % W, cm2 = pm2 % W, cm3 = pm3 % W;

    ACC_DECL
    const int bw = (nh * 8 + wn * 2) * 64 + l;   // this wave's 2 co-groups

    int R0, R1, R2, R3, S0, S1, S2, S3;
    TAPVARS(0, R0,R1,R2,R3, S0,S1,S2,S3)
    v4i bP0,bP1, bQ0,bQ1;
    v4i aP0,aP1,aP2,aP3, aQ0,aQ1,aQ2,aQ3;
    B_LOADQ(bP, bw)                 // (tap0, kb0)
    A_READQ(aP, lhi)

#pragma unroll 1
    for (int tp = 0; tp < 9; ++tp) {
        const int tb = bw + tp * 4096;
        // kb0: prefetch (tp,1); compute (tp,0)
        B_LOADQ(bQ, tb + 1024)
        A_READQ(aQ, 4 + lhi)
        MFMA_Q(aP, bP)
        // kb1: prefetch (tp,2); compute (tp,1)
        B_LOADQ(bP, tb + 2048)
        A_READQ(aP, 8 + lhi)
        MFMA_Q(aQ, bQ)
        // kb2: prefetch (tp,3); compute (tp,2)
        B_LOADQ(bQ, tb + 3072)
        A_READQ(aQ, 12 + lhi)
        MFMA_Q(aP, bP)
        // kb3: next-tap vars; prefetch (tp+1,0); compute (tp,3)
        const int tpn = (tp < 8) ? tp + 1 : 8;
        int N0, N1, N2, N3, T0, T1, T2, T3;
        TAPVARS(tpn, N0,N1,N2,N3, T0,T1,T2,T3)
        B_LOADQ(bP, bw + tpn * 4096)
        { aP0 = xl[N0 + (lhi ^ T0)]; aP1 = xl[N1 + (lhi ^ T1)];
          aP2 = xl[N2 + (lhi ^ T2)]; aP3 = xl[N3 + (lhi ^ T3)]; }
        MFMA_Q(aQ, bQ)
        R0 = N0; R1 = N1; R2 = N2; R3 = N3;
        S0 = T0; S1 = T1; S2 = T2; S3 = T3;
    }

    // ---- epilogue: pixel-contiguous stores + per-channel stats ----
    const int cobase = nh * 128 + wn * 32;
    float s00=0,s01=0,s02=0,s03=0, s10=0,s11=0,s12=0,s13=0;
    float q00=0,q01=0,q02=0,q03=0, q10=0,q11=0,q12=0,q13=0;
    // per-pt output base (n*C*HW + pp), pixel = gp0 + pt*16 + llo
    const int n0 = gx0 / HW, n1 = gx1 / HW, n2 = gx2 / HW, n3 = gx3 / HW;
    const size_t nb0 = (size_t)n0 * (C * HW) + pm0;
    const size_t nb1 = (size_t)n1 * (C * HW) + pm1;
    const size_t nb2 = (size_t)n2 * (C * HW) + pm2;
    const size_t nb3 = (size_t)n3 * (C * HW) + pm3;

    EPIP(0) EPIP(1) EPIP(2) EPIP(3)

    REDC(0,0) REDC(0,1) REDC(0,2) REDC(0,3)
    REDC(1,0) REDC(1,1) REDC(1,2) REDC(1,3)
}

// ---------------------------------------------------------------------------
// Final: fused finalize (redundant per block) + out = clip(z*s+b, -1, 1)
// ---------------------------------------------------------------------------
__global__ void bn_clip_kernel(const float4* __restrict__ z,
                               const double* __restrict__ sum,
                               const double* __restrict__ sumsq,
                               const float* __restrict__ gamma,
                               const float* __restrict__ beta,
                               float4* __restrict__ out, int total4) {
    __shared__ float s_scale[C], s_shift[C];
    const int t = threadIdx.x;
    {
        double mean = sum[t] / (double)CNT;
        double var  = sumsq[t] / (double)CNT - mean * mean;
        double inv  = 1.0 / sqrt(var + 1e-5);
        s_scale[t] = (float)inv * gamma[t];
        s_shift[t] = beta[t] - (float)(mean * inv) * gamma[t];
    }
    __syncthreads();
    for (int i = blockIdx.x * blockDim.x + t; i < total4;
         i += gridDim.x * blockDim.x) {
        int c = (i / (HW / 4)) & (C - 1);
        float s = s_scale[c], b = s_shift[c];
        float4 v = z[i];
        v.x = fminf(1.f, fmaxf(-1.f, v.x * s + b));
        v.y = fminf(1.f, fmaxf(-1.f, v.y * s + b));
        v.z = fminf(1.f, fmaxf(-1.f, v.z * s + b));
        v.w = fminf(1.f, fmaxf(-1.f, v.w * s + b));
        out[i] = v;
    }
}

// ---------------------------------------------------------------------------
extern "C" void kernel_launch(void* const* d_in, const int* in_sizes, int n_in,
                              void* d_out, int out_size, void* d_ws, size_t ws_size,
                              hipStream_t stream) {
    const float* x  = (const float*)d_in[0];
    const float* w1 = (const float*)d_in[1];
    const float* w2 = (const float*)d_in[2];
    const float* g1 = (const float*)d_in[3];
    const float* b1 = (const float*)d_in[4];
    const float* g2 = (const float*)d_in[5];
    const float* b2 = (const float*)d_in[6];
    float* out = (float*)d_out;

    char* ws = (char*)d_ws;
    size_t off = 0;
    float* z2 = (float*)(ws + off);   off += (size_t)TOTAL * 4;        // 51.4 MB
    v4i* xb1  = (v4i*)(ws + off);     off += (size_t)GP * 16 * 16;     // 12.85 MB
    v4i* xb2  = (v4i*)(ws + off);     off += (size_t)GP * 16 * 16;     // 12.85 MB
    v4i* wbf1 = (v4i*)(ws + off);     off += (size_t)36864 * 16;       // 590 KB
    v4i* wbf2 = (v4i*)(ws + off);     off += (size_t)36864 * 16;
    double* stats = (double*)(ws + off); off += 4 * 256 * 8;
    double* sum1 = stats, *sumsq1 = stats + 256, *sum2 = stats + 512, *sumsq2 = stats + 768;

    // y1 (i16) lives in d_out as scratch; fully rewritten by bn_clip at the end
    short* y1 = (short*)d_out;

    // pre-pass: both weight packs (frag order) + x pack (i8 planes) + stats zero
    pack_all_kernel<<<288 + GP / 256, 256, 0, stream>>>(w1, w2, x, wbf1, wbf2, xb1, stats);

    dim3 cgrid(NBLK, 2);   // pixel-chunks x co-halves = 1568 blocks
    // conv1: y1 (i16) -> d_out scratch, fused BN1 stats
    bconv_mfma<false, short><<<cgrid, 256, 0, stream>>>(xb1, wbf1, nullptr, y1, sum1, sumsq1);
    // finalize1 (inline) + BN1 + hardtanh + binarize -> i8 planes
    bn_signpack_kernel<<<GP / 256, 256, 0, stream>>>(y1, sum1, sumsq1, g1, b1, xb2);
    // conv2 + residual, fused BN2 stats, z2 -> ws
    bconv_mfma<true, float><<<cgrid, 256, 0, stream>>>(xb2, wbf2, x, z2, sum2, sumsq2);
    // finalize2 (inline) + BN2 + hardtanh -> out
    bn_clip_kernel<<<4096, 256, 0, stream>>>((const float4*)z2, sum2, sumsq2, g2, b2,
                                             (float4*)out, TOTAL / 4);
}

// Round 6
// 226.037 us; speedup vs baseline: 1.7726x; 1.7726x over previous
//
#include <hip/hip_runtime.h>
#include <stdint.h>

typedef int v4i __attribute__((ext_vector_type(4)));

// Problem constants
constexpr int C     = 256;           // channels (in == out)
constexpr int H     = 28, W = 28;
constexpr int HW    = H * W;         // 784
constexpr int NB    = 64;            // batch
constexpr int GP    = NB * HW;       // 50176 flattened pixels
constexpr int CNT   = GP;            // per-channel reduction count
constexpr int TOTAL = NB * C * HW;   // 12,845,056
constexpr int MT    = 64;            // pixels per block (M-tile)
constexpr int NBLK  = GP / MT;       // 784 blocks, exact
constexpr int LROWS = 128;           // staged pixel rows: gp0-32 .. gp0+95
constexpr int GPB   = GP / 256;      // 196 pixel-blocks per channel-chunk

// ---------------------------------------------------------------------------
// Pre-pass (1 dispatch): weight packs (frag order) + x pack + stats zero.
// R11: x-part parallelized 16x — one thread per (gp, ch-chunk): 16 loads +
// one 16B write. R10 post-mortem: 196-block x-part = 0.8 blocks/CU,
// latency-bound (256 scalar loads/thread, ~3 waves/CU to hide them).
// Frag order (A and B identical): lane l holds ch = g*16 + (l&15),
// k = (l>>4)*16+e. wbf[((tp*4+kb)*16+g)*64+l]. +1 -> 0x01, -1 -> 0xFF.
// ---------------------------------------------------------------------------
__global__ void pack_all_kernel(const float* __restrict__ pw1, const float* __restrict__ pw2,
                                const float* __restrict__ x,
                                v4i* __restrict__ wbf1, v4i* __restrict__ wbf2,
                                v4i* __restrict__ xb, double* __restrict__ stats) {
    const int t = threadIdx.x;
    const int bid = blockIdx.x;
    if (bid < 288) {                       // 288*256 = 73728 = 2 * 36864
        const int gid = bid * 256 + t;
        const bool second = (gid >= 36864);
        const float* w = second ? pw2 : pw1;
        v4i* dst       = second ? wbf2 : wbf1;
        const int idx = second ? gid - 36864 : gid;   // ((tp*4+kb)*16+g)*64+l
        const int l  = idx & 63;
        const int g  = (idx >> 6) & 15;
        const int kb = (idx >> 10) & 3;
        const int tp = idx >> 12;          // 0..8
        const int co  = g * 16 + (l & 15);
        const int ci0 = kb * 64 + (l >> 4) * 16;
        int b0 = 0, b1 = 0, b2 = 0, b3 = 0;
#pragma unroll
        for (int e = 0; e < 16; ++e) {
            float v = w[((size_t)co * C + ci0 + e) * 9 + tp];
            int b = (v < 0.f) ? 0xFF : 0x01;
            int sh = (e & 3) * 8;
            if (e < 4) b0 |= b << sh; else if (e < 8) b1 |= b << sh;
            else if (e < 12) b2 |= b << sh; else b3 |= b << sh;
        }
        v4i o; o.x = b0; o.y = b1; o.z = b2; o.w = b3;
        dst[idx] = o;
    } else {
        // x-part: 3136 blocks; ch-chunk = local/196, gp = (local%196)*256+t
        const int local = bid - 288;
        const int ch = local / GPB;
        const int gp = (local % GPB) * 256 + t;
        if (ch == 0 && gp < 1024) stats[gp] = 0.0;   // blocks local 0..3
        const int n = gp / HW, p = gp % HW;
        const float* base = x + (size_t)n * C * HW + p + (size_t)(ch * 16) * HW;
        int b0 = 0, b1 = 0, b2 = 0, b3 = 0;
#pragma unroll
        for (int e = 0; e < 16; ++e) {
            float v = base[(size_t)e * HW];
            int b = (v < 0.f) ? 0xFF : 0x01;
            int sh = (e & 3) * 8;
            if (e < 4) b0 |= b << sh; else if (e < 8) b1 |= b << sh;
            else if (e < 12) b2 |= b << sh; else b3 |= b << sh;
        }
        v4i o; o.x = b0; o.y = b1; o.z = b2; o.w = b3;
        xb[(size_t)ch * GP + gp] = o;
    }
}

// ---------------------------------------------------------------------------
// Fused finalize (redundant per block) + BN + binarize -> i8 plane-major.
// R11: one thread per (gp, ch-chunk) — 16 i16 loads + one 16B write.
// ---------------------------------------------------------------------------
__global__ void bn_signpack_kernel(const short* __restrict__ y,
                                   const double* __restrict__ sum,
                                   const double* __restrict__ sumsq,
                                   const float* __restrict__ gamma,
                                   const float* __restrict__ beta,
                                   v4i* __restrict__ xb) {
    __shared__ float s_scale[C], s_shift[C];
    const int t = threadIdx.x;
    {
        double mean = sum[t] / (double)CNT;
        double var  = sumsq[t] / (double)CNT - mean * mean;
        double inv  = 1.0 / sqrt(var + 1e-5);
        s_scale[t] = (float)inv * gamma[t];
        s_shift[t] = beta[t] - (float)(mean * inv) * gamma[t];
    }
    __syncthreads();
    const int local = blockIdx.x;          // 3136 blocks
    const int ch = local / GPB;
    const int gp = (local % GPB) * 256 + t;
    const int n = gp / HW, p = gp % HW;
    const short* base = y + (size_t)n * C * HW + p + (size_t)(ch * 16) * HW;
    int b0 = 0, b1 = 0, b2 = 0, b3 = 0;
#pragma unroll
    for (int e = 0; e < 16; ++e) {
        const int c = ch * 16 + e;
        float z = (float)base[(size_t)e * HW] * s_scale[c] + s_shift[c];
        int b = (z < 0.f) ? 0xFF : 0x01;
        int sh = (e & 3) * 8;
        if (e < 4) b0 |= b << sh; else if (e < 8) b1 |= b << sh;
        else if (e < 12) b2 |= b << sh; else b3 |= b << sh;
    }
    v4i o; o.x = b0; o.y = b1; o.z = b2; o.w = b3;
    xb[(size_t)ch * GP + gp] = o;
}

// ---------------------------------------------------------------------------
// R11 bconv: EXACT revert to R9/Round-4 structure (best measured: 88 us,
// MfmaUtil 12.6) + s_setprio around MFMA clusters (waves are barrier-free /
// independent here — the regime where setprio measured +4-7%).
// R10 post-mortem: N-split halved MFMA/block but kept staging + A-read +
// tap-var costs -> per-MFMA overhead ~2x, MfmaUtil 8.6, dur 134. Reverted.
// ---------------------------------------------------------------------------

#define ACC_DECL v4i c00={0,0,0,0},c01={0,0,0,0},c02={0,0,0,0},c03={0,0,0,0}, \
                     c10={0,0,0,0},c11={0,0,0,0},c12={0,0,0,0},c13={0,0,0,0}, \
                     c20={0,0,0,0},c21={0,0,0,0},c22={0,0,0,0},c23={0,0,0,0}, \
                     c30={0,0,0,0},c31={0,0,0,0},c32={0,0,0,0},c33={0,0,0,0};

#define MFMA(a,b,c) c = __builtin_amdgcn_mfma_i32_16x16x64_i8(a, b, c, 0, 0, 0);

// load 4 B-frags (one kb: nt=0..3) into P##0..3
#define B_LOADQ(P, idx) { const v4i* bp = wbf + (idx); \
    P##0 = bp[0]; P##1 = bp[64]; P##2 = bp[128]; P##3 = bp[192]; }

// read 4 A-frags (one kb: mt=0..3); R* = row*16 (or zero-row 2048), S* = swizzle
#define A_READQ(P, cb) { \
    P##0 = xl[R0 + ((cb) ^ S0)]; P##1 = xl[R1 + ((cb) ^ S1)]; \
    P##2 = xl[R2 + ((cb) ^ S2)]; P##3 = xl[R3 + ((cb) ^ S3)]; }

// 16 MFMAs: A frags (mt) x B frags (nt), setprio-wrapped
#define MFMA_Q(A,B) \
    __builtin_amdgcn_s_setprio(1); \
    MFMA(A##0,B##0,c00) MFMA(A##1,B##0,c10) MFMA(A##2,B##0,c20) MFMA(A##3,B##0,c30) \
    MFMA(A##0,B##1,c01) MFMA(A##1,B##1,c11) MFMA(A##2,B##1,c21) MFMA(A##3,B##1,c31) \
    MFMA(A##0,B##2,c02) MFMA(A##1,B##2,c12) MFMA(A##2,B##2,c22) MFMA(A##3,B##2,c32) \
    MFMA(A##0,B##3,c03) MFMA(A##1,B##3,c13) MFMA(A##2,B##3,c23) MFMA(A##3,B##3,c33) \
    __builtin_amdgcn_s_setprio(0);

// per-tap A addressing (rows*16 with zero-row select + swizzle)
#define TAPVARS(TPX, RD0,RD1,RD2,RD3, SD0,SD1,SD2,SD3) { \
    const int dr = (TPX)/3 - 1, dc = (TPX)%3 - 1; \
    const int lrb = 32 + llo + dr * W + dc; \
    const int sm = lrb & 15; \
    const bool m0 = ((unsigned)(cm0+dc) < 28u) && ((unsigned)(rm0+dr) < 28u); \
    const bool m1 = ((unsigned)(cm1+dc) < 28u) && ((unsigned)(rm1+dr) < 28u); \
    const bool m2 = ((unsigned)(cm2+dc) < 28u) && ((unsigned)(rm2+dr) < 28u); \
    const bool m3 = ((unsigned)(cm3+dc) < 28u) && ((unsigned)(rm3+dr) < 28u); \
    RD0 = m0 ? lrb*16        : 2048; SD0 = m0 ? sm : 0; \
    RD1 = m1 ? lrb*16 + 256  : 2048; SD1 = m1 ? sm : 0; \
    RD2 = m2 ? lrb*16 + 512  : 2048; SD2 = m2 ? sm : 0; \
    RD3 = m3 ? lrb*16 + 768  : 2048; SD3 = m3 ? sm : 0; }

// epilogue: one C frag (mt,ntl) -> vectorized store + stats
#define EPIV(mt,ntl) { \
    const int gpv = gp0 + (mt)*16 + lhi*4; \
    const int nn = gpv / HW; const int pp = gpv - nn*HW; \
    const size_t base = (size_t)nn*(C*HW) + (size_t)(wn*64+(ntl)*16+llo)*HW + pp; \
    const v4i cc = c##mt##ntl; \
    if constexpr (HAS_RES) { \
        const float4 r = *(const float4*)(residual + base); \
        float4 o; o.x = (float)cc.x + r.x; o.y = (float)cc.y + r.y; \
        o.z = (float)cc.z + r.z; o.w = (float)cc.w + r.w; \
        *(float4*)((float*)yout + base) = o; \
        sy##ntl += o.x + o.y + o.z + o.w; \
        sq##ntl += o.x*o.x + o.y*o.y + o.z*o.z + o.w*o.w; \
    } else { \
        int2 o; o.x = (cc.x & 0xFFFF) | (cc.y << 16); \
        o.y = (cc.z & 0xFFFF) | (cc.w << 16); \
        *(int2*)((short*)yout + base) = o; \
        const float fx = (float)cc.x, fy = (float)cc.y, fz = (float)cc.z, fw = (float)cc.w; \
        sy##ntl += fx + fy + fz + fw; \
        sq##ntl += fx*fx + fy*fy + fz*fz + fw*fw; \
    } }

#define REDN(ntl) { float s1 = sy##ntl, s2 = sq##ntl; \
    s1 += __shfl_down(s1, 32); s1 += __shfl_down(s1, 16); \
    s2 += __shfl_down(s2, 32); s2 += __shfl_down(s2, 16); \
    if (l < 16) { const int co = wn*64 + (ntl)*16 + l; \
        atomicAdd(&sum[co], (double)s1); atomicAdd(&sumsq[co], (double)s2); } }

template<bool HAS_RES, typename OUT_T>
__launch_bounds__(256, 3)
__global__ void bconv_mfma(const v4i* __restrict__ xb,
                           const v4i* __restrict__ wbf,
                           const float* __restrict__ residual,
                           OUT_T* __restrict__ yout,
                           double* __restrict__ sum, double* __restrict__ sumsq) {
    __shared__ v4i xl[LROWS * 16 + 16];     // 128 data rows + 1 zero row (33 KB)
    const int t   = threadIdx.x;
    const int gp0 = blockIdx.x * MT;

    // stage 128 pixel-rows x 16 chunks, coalesced reads, swizzled LDS writes
#pragma unroll
    for (int pass = 0; pass < 8; ++pass) {
        const int i = pass * 256 + t;
        const int c = i >> 7;               // plane 0..15
        const int r = i & 127;              // local row
        int gsrc = min(max(gp0 - 32 + r, 0), GP - 1);
        xl[r * 16 + (c ^ (r & 15))] = xb[(size_t)c * GP + gsrc];
    }
    if (t < 16) { v4i z = {0,0,0,0}; xl[LROWS * 16 + t] = z; }   // zero row
    __syncthreads();

    const int l = t & 63, wn = t >> 6;
    const int llo = l & 15, lhi = l >> 4;

    // per-m-tile pixel coords (pixel row of A-frag = llo)
    const int gx0 = gp0 + llo, gx1 = gx0 + 16, gx2 = gx0 + 32, gx3 = gx0 + 48;
    const int pm0 = gx0 % HW, pm1 = gx1 % HW, pm2 = gx2 % HW, pm3 = gx3 % HW;
    const int rm0 = pm0 / W, rm1 = pm1 / W, rm2 = pm2 / W, rm3 = pm3 / W;
    const int cm0 = pm0 % W, cm1 = pm1 % W, cm2 = pm2 % W, cm3 = pm3 % W;

    ACC_DECL
    const int bw = wn * 256 + l;

    int R0, R1, R2, R3, S0, S1, S2, S3;
    TAPVARS(0, R0,R1,R2,R3, S0,S1,S2,S3)
    v4i bP0,bP1,bP2,bP3, bQ0,bQ1,bQ2,bQ3;
    v4i aP0,aP1,aP2,aP3, aQ0,aQ1,aQ2,aQ3;
    B_LOADQ(bP, bw)                 // (tap0, kb0)
    A_READQ(aP, lhi)

#pragma unroll 1
    for (int tp = 0; tp < 9; ++tp) {
        const int tb = bw + tp * 4096;
        // kb0: prefetch (tp,1); compute (tp,0)
        B_LOADQ(bQ, tb + 1024)
        A_READQ(aQ, 4 + lhi)
        MFMA_Q(aP, bP)
        // kb1: prefetch (tp,2); compute (tp,1)
        B_LOADQ(bP, tb + 2048)
        A_READQ(aP, 8 + lhi)
        MFMA_Q(aQ, bQ)
        // kb2: prefetch (tp,3); compute (tp,2)
        B_LOADQ(bQ, tb + 3072)
        A_READQ(aQ, 12 + lhi)
        MFMA_Q(aP, bP)
        // kb3: next-tap vars; prefetch (tp+1,0); compute (tp,3)
        const int tpn = (tp < 8) ? tp + 1 : 8;
        int N0, N1, N2, N3, T0, T1, T2, T3;
        TAPVARS(tpn, N0,N1,N2,N3, T0,T1,T2,T3)
        B_LOADQ(bP, bw + tpn * 4096)
        { aP0 = xl[N0 + (lhi ^ T0)]; aP1 = xl[N1 + (lhi ^ T1)];
          aP2 = xl[N2 + (lhi ^ T2)]; aP3 = xl[N3 + (lhi ^ T3)]; }
        MFMA_Q(aQ, bQ)
        R0 = N0; R1 = N1; R2 = N2; R3 = N3;
        S0 = T0; S1 = T1; S2 = T2; S3 = T3;
    }

    // ---- epilogue: vectorized store + per-channel stats ----
    float sy0 = 0, sy1 = 0, sy2 = 0, sy3 = 0;
    float sq0 = 0, sq1 = 0, sq2 = 0, sq3 = 0;
    EPIV(0,0) EPIV(0,1) EPIV(0,2) EPIV(0,3)
    EPIV(1,0) EPIV(1,1) EPIV(1,2) EPIV(1,3)
    EPIV(2,0) EPIV(2,1) EPIV(2,2) EPIV(2,3)
    EPIV(3,0) EPIV(3,1) EPIV(3,2) EPIV(3,3)
    REDN(0) REDN(1) REDN(2) REDN(3)
}

// ---------------------------------------------------------------------------
// Final: fused finalize (redundant per block) + out = clip(z*s+b, -1, 1)
// ---------------------------------------------------------------------------
__global__ void bn_clip_kernel(const float4* __restrict__ z,
                               const double* __restrict__ sum,
                               const double* __restrict__ sumsq,
                               const float* __restrict__ gamma,
                               const float* __restrict__ beta,
                               float4* __restrict__ out, int total4) {
    __shared__ float s_scale[C], s_shift[C];
    const int t = threadIdx.x;
    {
        double mean = sum[t] / (double)CNT;
        double var  = sumsq[t] / (double)CNT - mean * mean;
        double inv  = 1.0 / sqrt(var + 1e-5);
        s_scale[t] = (float)inv * gamma[t];
        s_shift[t] = beta[t] - (float)(mean * inv) * gamma[t];
    }
    __syncthreads();
    for (int i = blockIdx.x * blockDim.x + t; i < total4;
         i += gridDim.x * blockDim.x) {
        int c = (i / (HW / 4)) & (C - 1);
        float s = s_scale[c], b = s_shift[c];
        float4 v = z[i];
        v.x = fminf(1.f, fmaxf(-1.f, v.x * s + b));
        v.y = fminf(1.f, fmaxf(-1.f, v.y * s + b));
        v.z = fminf(1.f, fmaxf(-1.f, v.z * s + b));
        v.w = fminf(1.f, fmaxf(-1.f, v.w * s + b));
        out[i] = v;
    }
}

// ---------------------------------------------------------------------------
extern "C" void kernel_launch(void* const* d_in, const int* in_sizes, int n_in,
                              void* d_out, int out_size, void* d_ws, size_t ws_size,
                              hipStream_t stream) {
    const float* x  = (const float*)d_in[0];
    const float* w1 = (const float*)d_in[1];
    const float* w2 = (const float*)d_in[2];
    const float* g1 = (const float*)d_in[3];
    const float* b1 = (const float*)d_in[4];
    const float* g2 = (const float*)d_in[5];
    const float* b2 = (const float*)d_in[6];
    float* out = (float*)d_out;

    char* ws = (char*)d_ws;
    size_t off = 0;
    float* z2 = (float*)(ws + off);   off += (size_t)TOTAL * 4;        // 51.4 MB
    v4i* xb1  = (v4i*)(ws + off);     off += (size_t)GP * 16 * 16;     // 12.85 MB
    v4i* xb2  = (v4i*)(ws + off);     off += (size_t)GP * 16 * 16;     // 12.85 MB
    v4i* wbf1 = (v4i*)(ws + off);     off += (size_t)36864 * 16;       // 590 KB
    v4i* wbf2 = (v4i*)(ws + off);     off += (size_t)36864 * 16;
    double* stats = (double*)(ws + off); off += 4 * 256 * 8;
    double* sum1 = stats, *sumsq1 = stats + 256, *sum2 = stats + 512, *sumsq2 = stats + 768;

    // y1 (i16) lives in d_out as scratch; fully rewritten by bn_clip at the end
    short* y1 = (short*)d_out;

    // pre-pass: weight packs (frag order) + x pack (parallel) + stats zero
    pack_all_kernel<<<288 + 16 * GPB, 256, 0, stream>>>(w1, w2, x, wbf1, wbf2, xb1, stats);

    // conv1: y1 (i16) -> d_out scratch, fused BN1 stats
    bconv_mfma<false, short><<<NBLK, 256, 0, stream>>>(xb1, wbf1, nullptr, y1, sum1, sumsq1);
    // finalize1 (inline) + BN1 + hardtanh + binarize -> i8 planes (parallel)
    bn_signpack_kernel<<<16 * GPB, 256, 0, stream>>>(y1, sum1, sumsq1, g1, b1, xb2);
    // conv2 + residual, fused BN2 stats, z2 -> ws
    bconv_mfma<true, float><<<NBLK, 256, 0, stream>>>(xb2, wbf2, x, z2, sum2, sumsq2);
    // finalize2 (inline) + BN2 + hardtanh -> out
    bn_clip_kernel<<<4096, 256, 0, stream>>>((const float4*)z2, sum2, sumsq2, g2, b2,
                                             (float4*)out, TOTAL / 4);
}